// Round 2
// baseline (1356.068 us; speedup 1.0000x reference)
//
#include <hip/hip_runtime.h>
#include <math.h>

// InstantNGP-style hash-grid encoder, 16 levels, FEAT=2, B=2M points.
// Level metadata replayed from the reference's level_meta() (verified by hand):
//   res:    ceil(16*exp(i*ln(128)/15) - 1) + 1
//   dense levels 0..4 (res^3 <= 2^19), hashed levels 5..15 (size = 2^19)
#define NLEVELS 16
#define BEGIN_FAST 5

// compile-time constants (so the optimizer sees literals for magic-div)
constexpr unsigned kRes[NLEVELS] = {16u, 23u, 31u, 43u, 59u, 81u, 112u, 154u, 213u, 295u, 407u, 562u, 777u, 1073u, 1483u, 2048u};
constexpr unsigned kSize[NLEVELS] = {
    4096u,    // 16^3
    12168u,   // align8(23^3=12167)
    29792u,   // align8(31^3=29791)
    79512u,   // align8(43^3=79507)
    205384u,  // align8(59^3=205379)
    524288u, 524288u, 524288u, 524288u, 524288u, 524288u,
    524288u, 524288u, 524288u, 524288u, 524288u};
constexpr unsigned kOffset[NLEVELS] = {
    0u,       4096u,    16264u,   46056u,   125568u,  330952u,
    855240u,  1379528u, 1903816u, 2428104u, 2952392u, 3476680u,
    4000968u, 4525256u, 5049544u, 5573832u};

struct Scales {
    float s[NLEVELS];
};

typedef float fvec4 __attribute__((ext_vector_type(4)));

__global__ __launch_bounds__(256) void hash_encode_kernel(
    const float* __restrict__ positions,  // [B,3]
    const float2* __restrict__ table,     // [TOTAL,2] viewed as float2 rows
    float* __restrict__ out,              // [B,32]
    int B, Scales sc)
{
    int p = blockIdx.x * 256 + threadIdx.x;
    if (p >= B) return;

    const float x = positions[3 * p + 0];
    const float y = positions[3 * p + 1];
    const float z = positions[3 * p + 2];

    float o[2 * NLEVELS];

#pragma unroll
    for (int l = 0; l < NLEVELS; ++l) {
        const float s = sc.s[l];
        // match reference: pos = positions*scale + 0.5 (fp32)
        const float px = x * s + 0.5f;
        const float py = y * s + 0.5f;
        const float pz = z * s + 0.5f;
        const float flx = floorf(px);
        const float fly = floorf(py);
        const float flz = floorf(pz);
        const float rx = px - flx;
        const float ry = py - fly;
        const float rz = pz - flz;
        const unsigned gx = (unsigned)flx;
        const unsigned gy = (unsigned)fly;
        const unsigned gz = (unsigned)flz;
        const float wx0 = 1.0f - rx, wy0 = 1.0f - ry, wz0 = 1.0f - rz;

        float ax = 0.0f, ay = 0.0f;
#pragma unroll
        for (int c = 0; c < 8; ++c) {
            const unsigned cx = (unsigned)(c & 1);
            const unsigned cy = (unsigned)((c >> 1) & 1);
            const unsigned cz = (unsigned)((c >> 2) & 1);
            const unsigned pgx = gx + cx;
            const unsigned pgy = gy + cy;
            const unsigned pgz = gz + cz;
            const float w = (cx ? rx : wx0) * (cy ? ry : wy0) * (cz ? rz : wz0);
            unsigned h;
            if (l < BEGIN_FAST) {
                h = pgx + pgy * kRes[l] + pgz * (kRes[l] * kRes[l]);
            } else {
                h = pgx ^ (pgy * 2654435761u) ^ (pgz * 805459861u);
            }
            const unsigned idx = (h % kSize[l]) + kOffset[l];
            const float2 t = table[idx];
            ax += w * t.x;
            ay += w * t.y;
        }
        o[2 * l + 0] = ax;
        o[2 * l + 1] = ay;
    }

    // 128B contiguous per point: 8 x float4 non-temporal stores (output is
    // write-once, never re-read -> keep it out of L2 so table gathers stay hot)
    float* op = out + (size_t)p * (2 * NLEVELS);
#pragma unroll
    for (int i = 0; i < 8; ++i) {
        fvec4 v = {o[4 * i + 0], o[4 * i + 1], o[4 * i + 2], o[4 * i + 3]};
        __builtin_nontemporal_store(v, reinterpret_cast<fvec4*>(op) + i);
    }
}

extern "C" void kernel_launch(void* const* d_in, const int* in_sizes, int n_in,
                              void* d_out, int out_size, void* d_ws, size_t ws_size,
                              hipStream_t stream) {
    const float* positions = (const float*)d_in[0];
    const float* table = (const float*)d_in[1];
    float* out = (float*)d_out;

    const int B = in_sizes[0] / 3;

    // scales computed in double exactly like the reference (then cast to f32)
    Scales sc;
    const double log_b = log(2048.0 / 16.0) / (NLEVELS - 1);
    for (int l = 0; l < NLEVELS; ++l) {
        sc.s[l] = (float)(16.0 * exp((double)l * log_b) - 1.0);
    }

    const int blocks = (B + 255) / 256;
    hash_encode_kernel<<<blocks, 256, 0, stream>>>(
        positions, (const float2*)table, out, B, sc);
}

// Round 3
// 974.088 us; speedup vs baseline: 1.3921x; 1.3921x over previous
//
#include <hip/hip_runtime.h>
#include <math.h>

// InstantNGP-style hash-grid encoder, 16 levels, FEAT=2, B=2M points.
//   res:    ceil(16*exp(i*ln(128)/15) - 1) + 1
//   dense levels 0..4 (res^3 <= 2^19), hashed levels 5..15 (size = 2^19 each)
//
// Strategy: one kernel per fine (hashed) level -> its 4 MB table slice fits a
// per-XCD L2 exactly, so random gathers become L2 hits. Results staged in a
// transposed workspace ws[level][B] (coalesced float2 writes). A final kernel
// computes the 5 dense levels inline (2.65 MB tables, L2-resident), merges the
// ws slices, and writes the [B,32] output as coalesced 128B-per-point stores.
#define NLEVELS 16
#define BEGIN_FAST 5
#define P2 2654435761u
#define P3 805459861u
#define FAST_MASK 524287u  // size = 2^19 for all hashed levels

constexpr unsigned kRes[NLEVELS] = {16u, 23u, 31u, 43u, 59u, 81u, 112u, 154u, 213u, 295u, 407u, 562u, 777u, 1073u, 1483u, 2048u};
constexpr unsigned kSize[NLEVELS] = {
    4096u, 12168u, 29792u, 79512u, 205384u,
    524288u, 524288u, 524288u, 524288u, 524288u, 524288u,
    524288u, 524288u, 524288u, 524288u, 524288u};
constexpr unsigned kOffset[NLEVELS] = {
    0u,       4096u,    16264u,   46056u,   125568u,  330952u,
    855240u,  1379528u, 1903816u, 2428104u, 2952392u, 3476680u,
    4000968u, 4525256u, 5049544u, 5573832u};

struct Scales {
    float s[NLEVELS];
};

typedef float fvec4 __attribute__((ext_vector_type(4)));

// ---------------- fine (hashed) level: table slice pre-offset, 4MB, L2-fit ----
__global__ __launch_bounds__(256) void fine_level_kernel(
    const float* __restrict__ positions,  // [B,3]
    const float2* __restrict__ tab,       // table + level offset (524288 rows)
    float2* __restrict__ wsl,             // ws slice [B]
    int B, float s)
{
    int p = blockIdx.x * 256 + threadIdx.x;
    if (p >= B) return;

    const float x = positions[3 * p + 0];
    const float y = positions[3 * p + 1];
    const float z = positions[3 * p + 2];

    const float px = x * s + 0.5f;
    const float py = y * s + 0.5f;
    const float pz = z * s + 0.5f;
    const float flx = floorf(px), fly = floorf(py), flz = floorf(pz);
    const float rx = px - flx, ry = py - fly, rz = pz - flz;
    const unsigned gx = (unsigned)flx;
    const unsigned gy = (unsigned)fly;
    const unsigned gz = (unsigned)flz;
    const float wx0 = 1.0f - rx, wy0 = 1.0f - ry, wz0 = 1.0f - rz;

    const unsigned hy0 = gy * P2, hy1 = hy0 + P2;
    const unsigned hz0 = gz * P3, hz1 = hz0 + P3;

    float ax = 0.0f, ay = 0.0f;
#pragma unroll
    for (int c = 0; c < 8; ++c) {
        const unsigned cx = (unsigned)(c & 1);
        const unsigned cy = (unsigned)((c >> 1) & 1);
        const unsigned cz = (unsigned)((c >> 2) & 1);
        const float w = (cx ? rx : wx0) * (cy ? ry : wy0) * (cz ? rz : wz0);
        const unsigned h = (gx + cx) ^ (cy ? hy1 : hy0) ^ (cz ? hz1 : hz0);
        const float2 t = tab[h & FAST_MASK];
        ax += w * t.x;
        ay += w * t.y;
    }
    wsl[p] = make_float2(ax, ay);
}

// ------------- final: dense levels inline + merge ws + coalesced out ---------
__global__ __launch_bounds__(256) void final_kernel(
    const float* __restrict__ positions,  // [B,3]
    const float2* __restrict__ table,     // full table
    const float2* __restrict__ ws,        // [11][B] slices for levels 5..15
    float* __restrict__ out,              // [B,32]
    int B, Scales sc)
{
    int p = blockIdx.x * 256 + threadIdx.x;
    if (p >= B) return;

    const float x = positions[3 * p + 0];
    const float y = positions[3 * p + 1];
    const float z = positions[3 * p + 2];

    float o[2 * NLEVELS];

#pragma unroll
    for (int l = 0; l < BEGIN_FAST; ++l) {
        const float s = sc.s[l];
        const float px = x * s + 0.5f;
        const float py = y * s + 0.5f;
        const float pz = z * s + 0.5f;
        const float flx = floorf(px), fly = floorf(py), flz = floorf(pz);
        const float rx = px - flx, ry = py - fly, rz = pz - flz;
        const unsigned gx = (unsigned)flx;
        const unsigned gy = (unsigned)fly;
        const unsigned gz = (unsigned)flz;
        const float wx0 = 1.0f - rx, wy0 = 1.0f - ry, wz0 = 1.0f - rz;

        float ax = 0.0f, ay = 0.0f;
#pragma unroll
        for (int c = 0; c < 8; ++c) {
            const unsigned cx = (unsigned)(c & 1);
            const unsigned cy = (unsigned)((c >> 1) & 1);
            const unsigned cz = (unsigned)((c >> 2) & 1);
            const float w = (cx ? rx : wx0) * (cy ? ry : wy0) * (cz ? rz : wz0);
            const unsigned h = (gx + cx) + (gy + cy) * kRes[l] + (gz + cz) * (kRes[l] * kRes[l]);
            const float2 t = table[(h % kSize[l]) + kOffset[l]];
            ax += w * t.x;
            ay += w * t.y;
        }
        o[2 * l + 0] = ax;
        o[2 * l + 1] = ay;
    }

#pragma unroll
    for (int l = BEGIN_FAST; l < NLEVELS; ++l) {
        const float2 v = ws[(size_t)(l - BEGIN_FAST) * (size_t)B + p];
        o[2 * l + 0] = v.x;
        o[2 * l + 1] = v.y;
    }

    float* op = out + (size_t)p * (2 * NLEVELS);
#pragma unroll
    for (int i = 0; i < 8; ++i) {
        fvec4 v = {o[4 * i + 0], o[4 * i + 1], o[4 * i + 2], o[4 * i + 3]};
        *(reinterpret_cast<fvec4*>(op) + i) = v;
    }
}

// ---------------- fallback: monolithic (if ws too small) ---------------------
__global__ __launch_bounds__(256) void hash_encode_kernel(
    const float* __restrict__ positions,
    const float2* __restrict__ table,
    float* __restrict__ out,
    int B, Scales sc)
{
    int p = blockIdx.x * 256 + threadIdx.x;
    if (p >= B) return;

    const float x = positions[3 * p + 0];
    const float y = positions[3 * p + 1];
    const float z = positions[3 * p + 2];

    float o[2 * NLEVELS];

#pragma unroll
    for (int l = 0; l < NLEVELS; ++l) {
        const float s = sc.s[l];
        const float px = x * s + 0.5f;
        const float py = y * s + 0.5f;
        const float pz = z * s + 0.5f;
        const float flx = floorf(px), fly = floorf(py), flz = floorf(pz);
        const float rx = px - flx, ry = py - fly, rz = pz - flz;
        const unsigned gx = (unsigned)flx;
        const unsigned gy = (unsigned)fly;
        const unsigned gz = (unsigned)flz;
        const float wx0 = 1.0f - rx, wy0 = 1.0f - ry, wz0 = 1.0f - rz;

        float ax = 0.0f, ay = 0.0f;
#pragma unroll
        for (int c = 0; c < 8; ++c) {
            const unsigned cx = (unsigned)(c & 1);
            const unsigned cy = (unsigned)((c >> 1) & 1);
            const unsigned cz = (unsigned)((c >> 2) & 1);
            const unsigned pgx = gx + cx;
            const unsigned pgy = gy + cy;
            const unsigned pgz = gz + cz;
            const float w = (cx ? rx : wx0) * (cy ? ry : wy0) * (cz ? rz : wz0);
            unsigned h;
            if (l < BEGIN_FAST) {
                h = pgx + pgy * kRes[l] + pgz * (kRes[l] * kRes[l]);
            } else {
                h = pgx ^ (pgy * P2) ^ (pgz * P3);
            }
            const unsigned idx = (h % kSize[l]) + kOffset[l];
            const float2 t = table[idx];
            ax += w * t.x;
            ay += w * t.y;
        }
        o[2 * l + 0] = ax;
        o[2 * l + 1] = ay;
    }

    float* op = out + (size_t)p * (2 * NLEVELS);
#pragma unroll
    for (int i = 0; i < 8; ++i) {
        fvec4 v = {o[4 * i + 0], o[4 * i + 1], o[4 * i + 2], o[4 * i + 3]};
        *(reinterpret_cast<fvec4*>(op) + i) = v;
    }
}

extern "C" void kernel_launch(void* const* d_in, const int* in_sizes, int n_in,
                              void* d_out, int out_size, void* d_ws, size_t ws_size,
                              hipStream_t stream) {
    const float* positions = (const float*)d_in[0];
    const float2* table = (const float2*)d_in[1];
    float* out = (float*)d_out;

    const int B = in_sizes[0] / 3;

    Scales sc;
    const double log_b = log(2048.0 / 16.0) / (NLEVELS - 1);
    for (int l = 0; l < NLEVELS; ++l) {
        sc.s[l] = (float)(16.0 * exp((double)l * log_b) - 1.0);
    }

    const int blocks = (B + 255) / 256;
    const size_t ws_need = (size_t)(NLEVELS - BEGIN_FAST) * (size_t)B * sizeof(float2);

    if (ws_size >= ws_need) {
        float2* ws = (float2*)d_ws;
        for (int l = BEGIN_FAST; l < NLEVELS; ++l) {
            fine_level_kernel<<<blocks, 256, 0, stream>>>(
                positions, table + kOffset[l],
                ws + (size_t)(l - BEGIN_FAST) * (size_t)B,
                B, sc.s[l]);
        }
        final_kernel<<<blocks, 256, 0, stream>>>(positions, table, ws, out, B, sc);
    } else {
        hash_encode_kernel<<<blocks, 256, 0, stream>>>(positions, (const float*)table ? table : table, out, B, sc);
    }
}

// Round 4
// 828.709 us; speedup vs baseline: 1.6364x; 1.1754x over previous
//
#include <hip/hip_runtime.h>
#include <math.h>

// InstantNGP-style hash-grid encoder, 16 levels, FEAT=2, B=2M points.
//   res: ceil(16*exp(i*ln(128)/15) - 1) + 1
//   dense levels 0..4 (res^3 <= 2^19), hashed levels 5..15 (size = 2^19 each)
//
// Structure (full path, ws >= 16 slices):
//   - 11x fine_level_kernel: one per hashed level; its 4 MB table slice fits a
//     per-XCD L2. Streaming traffic (positions in, ws out) is non-temporal so
//     it doesn't evict the table from L2. Writes ws slice [l][B] coalesced.
//   - dense_kernel: levels 0..4 inline (2.65 MB of tables, L2-resident),
//     x-paired float4 gathers (corner cx=1 is entry idx+1 mod size; rare wrap
//     fixed up by a predicated reload). Writes ws slices 0..4.
//   - merge_kernel: pure streaming, no gathers: 16 coalesced slice reads ->
//     one 128B-per-point coalesced output write. Should run near HBM BW.
#define NLEVELS 16
#define BEGIN_FAST 5
#define P2 2654435761u
#define P3 805459861u
#define FAST_MASK 524287u  // size = 2^19 for all hashed levels

constexpr unsigned kRes[NLEVELS] = {16u, 23u, 31u, 43u, 59u, 81u, 112u, 154u, 213u, 295u, 407u, 562u, 777u, 1073u, 1483u, 2048u};
constexpr unsigned kSize[NLEVELS] = {
    4096u, 12168u, 29792u, 79512u, 205384u,
    524288u, 524288u, 524288u, 524288u, 524288u, 524288u,
    524288u, 524288u, 524288u, 524288u, 524288u};
constexpr unsigned kOffset[NLEVELS] = {
    0u,       4096u,    16264u,   46056u,   125568u,  330952u,
    855240u,  1379528u, 1903816u, 2428104u, 2952392u, 3476680u,
    4000968u, 4525256u, 5049544u, 5573832u};

struct Scales {
    float s[NLEVELS];
};

typedef float fvec2 __attribute__((ext_vector_type(2)));
typedef float fvec4 __attribute__((ext_vector_type(4)));
typedef float fvec4a8 __attribute__((ext_vector_type(4), aligned(8)));

// ---------------- fine (hashed) level: table slice pre-offset, 4MB, L2-fit ---
__global__ __launch_bounds__(256) void fine_level_kernel(
    const float* __restrict__ positions,  // [B,3]
    const float2* __restrict__ tab,       // table + level offset (524288 rows)
    float2* __restrict__ wsl,             // ws slice [B]
    int B, float s)
{
    int p = blockIdx.x * 256 + threadIdx.x;
    if (p >= B) return;

    const float x = __builtin_nontemporal_load(positions + 3 * p + 0);
    const float y = __builtin_nontemporal_load(positions + 3 * p + 1);
    const float z = __builtin_nontemporal_load(positions + 3 * p + 2);

    const float px = x * s + 0.5f;
    const float py = y * s + 0.5f;
    const float pz = z * s + 0.5f;
    const float flx = floorf(px), fly = floorf(py), flz = floorf(pz);
    const float rx = px - flx, ry = py - fly, rz = pz - flz;
    const unsigned gx = (unsigned)flx;
    const unsigned gy = (unsigned)fly;
    const unsigned gz = (unsigned)flz;
    const float wx0 = 1.0f - rx, wy0 = 1.0f - ry, wz0 = 1.0f - rz;

    const unsigned hy0 = gy * P2, hy1 = hy0 + P2;
    const unsigned hz0 = gz * P3, hz1 = hz0 + P3;

    float ax = 0.0f, ay = 0.0f;
#pragma unroll
    for (int c = 0; c < 8; ++c) {
        const unsigned cx = (unsigned)(c & 1);
        const unsigned cy = (unsigned)((c >> 1) & 1);
        const unsigned cz = (unsigned)((c >> 2) & 1);
        const float w = (cx ? rx : wx0) * (cy ? ry : wy0) * (cz ? rz : wz0);
        const unsigned h = (gx + cx) ^ (cy ? hy1 : hy0) ^ (cz ? hz1 : hz0);
        const float2 t = tab[h & FAST_MASK];
        ax += w * t.x;
        ay += w * t.y;
    }
    fvec2 r = {ax, ay};
    __builtin_nontemporal_store(r, reinterpret_cast<fvec2*>(wsl) + p);
}

// ---------------- dense levels 0..4 -> ws slices 0..4 ------------------------
__global__ __launch_bounds__(256) void dense_kernel(
    const float* __restrict__ positions,  // [B,3]
    const float2* __restrict__ table,     // full table
    float2* __restrict__ ws,              // slices [16][B]; writes 0..4
    int B, Scales sc)
{
    int p = blockIdx.x * 256 + threadIdx.x;
    if (p >= B) return;

    const float x = __builtin_nontemporal_load(positions + 3 * p + 0);
    const float y = __builtin_nontemporal_load(positions + 3 * p + 1);
    const float z = __builtin_nontemporal_load(positions + 3 * p + 2);

#pragma unroll
    for (int l = 0; l < BEGIN_FAST; ++l) {
        const float s = sc.s[l];
        const float px = x * s + 0.5f;
        const float py = y * s + 0.5f;
        const float pz = z * s + 0.5f;
        const float flx = floorf(px), fly = floorf(py), flz = floorf(pz);
        const float rx = px - flx, ry = py - fly, rz = pz - flz;
        const unsigned gx = (unsigned)flx;
        const unsigned gy = (unsigned)fly;
        const unsigned gz = (unsigned)flz;
        const float wx0 = 1.0f - rx, wy0 = 1.0f - ry, wz0 = 1.0f - rz;

        const float2* tab = table + kOffset[l];
        const unsigned res = kRes[l];

        float ax = 0.0f, ay = 0.0f;
#pragma unroll
        for (int cc = 0; cc < 4; ++cc) {          // (cy, cz); x-pair fused
            const unsigned cy = (unsigned)(cc & 1);
            const unsigned cz = (unsigned)(cc >> 1);
            const float wyz = (cy ? ry : wy0) * (cz ? rz : wz0);
            const unsigned h0 = gx + (gy + cy) * res + (gz + cz) * (res * res);
            const unsigned idx0 = h0 % kSize[l];
            // entries idx0 (cx=0) and idx0+1 (cx=1) in one 16B load; the 8B
            // past the slice end is still inside `table`, patched below.
            const fvec4 tt = *reinterpret_cast<const fvec4a8*>(tab + idx0);
            float t1x = tt.z, t1y = tt.w;
            if (idx0 == kSize[l] - 1) {           // (h0+1) % size wrapped to 0
                const float2 tf = tab[0];
                t1x = tf.x; t1y = tf.y;
            }
            ax += wyz * (wx0 * tt.x + rx * t1x);
            ay += wyz * (wx0 * tt.y + rx * t1y);
        }
        fvec2 r = {ax, ay};
        __builtin_nontemporal_store(r, reinterpret_cast<fvec2*>(ws) + (size_t)l * (size_t)B + p);
    }
}

// ---------------- merge: pure streaming, no gathers --------------------------
__global__ __launch_bounds__(256) void merge_kernel(
    const float2* __restrict__ ws,  // [16][B]
    float* __restrict__ out,        // [B,32]
    int B)
{
    int p = blockIdx.x * 256 + threadIdx.x;
    if (p >= B) return;

    float o[2 * NLEVELS];
#pragma unroll
    for (int l = 0; l < NLEVELS; ++l) {
        const fvec2 v = __builtin_nontemporal_load(
            reinterpret_cast<const fvec2*>(ws) + (size_t)l * (size_t)B + p);
        o[2 * l + 0] = v.x;
        o[2 * l + 1] = v.y;
    }
    float* op = out + (size_t)p * (2 * NLEVELS);
#pragma unroll
    for (int i = 0; i < 8; ++i) {
        fvec4 v = {o[4 * i + 0], o[4 * i + 1], o[4 * i + 2], o[4 * i + 3]};
        *(reinterpret_cast<fvec4*>(op) + i) = v;
    }
}

// ------------- fallback final (ws holds only 11 fine slices) -----------------
__global__ __launch_bounds__(256) void final_kernel(
    const float* __restrict__ positions,
    const float2* __restrict__ table,
    const float2* __restrict__ ws,        // [11][B] slices for levels 5..15
    float* __restrict__ out,
    int B, Scales sc)
{
    int p = blockIdx.x * 256 + threadIdx.x;
    if (p >= B) return;

    const float x = positions[3 * p + 0];
    const float y = positions[3 * p + 1];
    const float z = positions[3 * p + 2];

    float o[2 * NLEVELS];

#pragma unroll
    for (int l = 0; l < BEGIN_FAST; ++l) {
        const float s = sc.s[l];
        const float px = x * s + 0.5f;
        const float py = y * s + 0.5f;
        const float pz = z * s + 0.5f;
        const float flx = floorf(px), fly = floorf(py), flz = floorf(pz);
        const float rx = px - flx, ry = py - fly, rz = pz - flz;
        const unsigned gx = (unsigned)flx;
        const unsigned gy = (unsigned)fly;
        const unsigned gz = (unsigned)flz;
        const float wx0 = 1.0f - rx, wy0 = 1.0f - ry, wz0 = 1.0f - rz;

        float ax = 0.0f, ay = 0.0f;
#pragma unroll
        for (int c = 0; c < 8; ++c) {
            const unsigned cx = (unsigned)(c & 1);
            const unsigned cy = (unsigned)((c >> 1) & 1);
            const unsigned cz = (unsigned)((c >> 2) & 1);
            const float w = (cx ? rx : wx0) * (cy ? ry : wy0) * (cz ? rz : wz0);
            const unsigned h = (gx + cx) + (gy + cy) * kRes[l] + (gz + cz) * (kRes[l] * kRes[l]);
            const float2 t = table[(h % kSize[l]) + kOffset[l]];
            ax += w * t.x;
            ay += w * t.y;
        }
        o[2 * l + 0] = ax;
        o[2 * l + 1] = ay;
    }

#pragma unroll
    for (int l = BEGIN_FAST; l < NLEVELS; ++l) {
        const float2 v = ws[(size_t)(l - BEGIN_FAST) * (size_t)B + p];
        o[2 * l + 0] = v.x;
        o[2 * l + 1] = v.y;
    }

    float* op = out + (size_t)p * (2 * NLEVELS);
#pragma unroll
    for (int i = 0; i < 8; ++i) {
        fvec4 v = {o[4 * i + 0], o[4 * i + 1], o[4 * i + 2], o[4 * i + 3]};
        *(reinterpret_cast<fvec4*>(op) + i) = v;
    }
}

extern "C" void kernel_launch(void* const* d_in, const int* in_sizes, int n_in,
                              void* d_out, int out_size, void* d_ws, size_t ws_size,
                              hipStream_t stream) {
    const float* positions = (const float*)d_in[0];
    const float2* table = (const float2*)d_in[1];
    float* out = (float*)d_out;

    const int B = in_sizes[0] / 3;

    Scales sc;
    const double log_b = log(2048.0 / 16.0) / (NLEVELS - 1);
    for (int l = 0; l < NLEVELS; ++l) {
        sc.s[l] = (float)(16.0 * exp((double)l * log_b) - 1.0);
    }

    const int blocks = (B + 255) / 256;
    const size_t slice_bytes = (size_t)B * sizeof(float2);
    float2* ws = (float2*)d_ws;

    if (ws_size >= (size_t)NLEVELS * slice_bytes) {
        // full path: 16 staged slices
        for (int l = BEGIN_FAST; l < NLEVELS; ++l) {
            fine_level_kernel<<<blocks, 256, 0, stream>>>(
                positions, table + kOffset[l],
                ws + (size_t)l * (size_t)B, B, sc.s[l]);
        }
        dense_kernel<<<blocks, 256, 0, stream>>>(positions, table, ws, B, sc);
        merge_kernel<<<blocks, 256, 0, stream>>>(ws, out, B);
    } else {
        // fallback: 11 fine slices + dense-inline final
        for (int l = BEGIN_FAST; l < NLEVELS; ++l) {
            fine_level_kernel<<<blocks, 256, 0, stream>>>(
                positions, table + kOffset[l],
                ws + (size_t)(l - BEGIN_FAST) * (size_t)B, B, sc.s[l]);
        }
        final_kernel<<<blocks, 256, 0, stream>>>(positions, table, ws, out, B, sc);
    }
}